// Round 1
// baseline (109.839 us; speedup 1.0000x reference)
//
#include <hip/hip_runtime.h>
#include <math.h>

// B=1024, D=128, H=128
#define Bn 1024
#define Dn 128
#define Hn 128

// One block per 4 rows of x (256 blocks = 1/CU), 256 threads:
//   g = threadIdx.x>>7 in {0,1} selects j-half, d = threadIdx.x&127 = column.
// Phase 1: all-pairs |x_i - x_j| column sums (the 268M-op bottleneck).
// Phase 2: combine halves -> dms (diffs_mean rows) in LDS.
// Phase 3: tau = clip(softplus(x.Wt+bt),0.01,inf)+1 per row (wave reduce).
// Phase 4: matvecs  m=(Wd.dm+bd)/tau ; y=relu(Wa.m+ba)+Wr.x+br.
// Phase 5: LayerNorm per row (wave reduce) -> out.
__global__ __launch_bounds__(256) void fused_resd1(
    const float* __restrict__ x,
    const float* __restrict__ Wd, const float* __restrict__ bd,
    const float* __restrict__ Wt, const float* __restrict__ bt,
    const float* __restrict__ Wa, const float* __restrict__ ba,
    const float* __restrict__ Wr, const float* __restrict__ br,
    const float* __restrict__ gamma, const float* __restrict__ beta,
    float* __restrict__ out) {
  const int t = threadIdx.x;
  const int d = t & 127;
  const int g = t >> 7;
  const int i0 = blockIdx.x << 2;

  __shared__ float xs[4][Dn];    // this block's 4 x-rows
  __shared__ float dms[4][Dn];   // diffs_mean rows
  __shared__ float ms[4][Hn];    // h_mean rows
  __shared__ float ys[4][Hn];    // pre-LN rows
  __shared__ float red[4][Dn];   // partial-sum combine
  __shared__ float wt_s[Dn];
  __shared__ float tau_s[4];     // stores 1/tau

  // ---- Phase 1: j-loop ----
  const float xi0 = x[(i0 + 0) * Dn + d];
  const float xi1 = x[(i0 + 1) * Dn + d];
  const float xi2 = x[(i0 + 2) * Dn + d];
  const float xi3 = x[(i0 + 3) * Dn + d];
  float a0 = 0.f, a1 = 0.f, a2 = 0.f, a3 = 0.f;
  const float* xp = x + (size_t)g * 512 * Dn + d;  // this group's j-half
#pragma unroll 1
  for (int j = 0; j < 512; j += 8) {
    float xj[8];
#pragma unroll
    for (int u = 0; u < 8; ++u) xj[u] = xp[(j + u) * Dn];
#pragma unroll
    for (int u = 0; u < 8; ++u) {
      a0 += fabsf(xi0 - xj[u]);
      a1 += fabsf(xi1 - xj[u]);
      a2 += fabsf(xi2 - xj[u]);
      a3 += fabsf(xi3 - xj[u]);
    }
  }

  // ---- Phase 2: combine the two j-halves ----
  if (g == 0) {
    red[0][d] = a0; red[1][d] = a1; red[2][d] = a2; red[3][d] = a3;
    xs[0][d] = xi0; xs[1][d] = xi1; xs[2][d] = xi2; xs[3][d] = xi3;
    wt_s[d] = Wt[d];
  }
  __syncthreads();
  if (g == 1) {
    const float s = 1.0f / 1024.0f;
    dms[0][d] = (red[0][d] + a0) * s;
    dms[1][d] = (red[1][d] + a1) * s;
    dms[2][d] = (red[2][d] + a2) * s;
    dms[3][d] = (red[3][d] + a3) * s;
  }
  __syncthreads();

  // ---- Phase 3: tau (one wave per row) ----
  {
    const int r = t >> 6, p = t & 63;
    float partial = xs[r][p] * wt_s[p] + xs[r][p + 64] * wt_s[p + 64];
#pragma unroll
    for (int off = 32; off; off >>= 1) partial += __shfl_xor(partial, off, 64);
    if (p == 0) {
      const float z = partial + bt[0];
      const float sp = fmaxf(z, 0.f) + log1pf(expf(-fabsf(z)));  // softplus
      tau_s[r] = 1.0f / (fmaxf(sp, 0.01f) + 1.0f);
    }
  }
  __syncthreads();

  // ---- Phase 4a: m = (Wd . dm + bd) / tau ----
  const int h = d;               // output feature
  const int r0 = 2 * g, r1 = 2 * g + 1;
  {
    float m0 = bd[h], m1 = m0;
    const float4* w = (const float4*)(Wd + (size_t)h * Dn);
#pragma unroll 4
    for (int k4 = 0; k4 < Dn / 4; ++k4) {
      const float4 wv = w[k4];
      const int k = k4 * 4;
      m0 += wv.x * dms[r0][k] + wv.y * dms[r0][k + 1] + wv.z * dms[r0][k + 2] + wv.w * dms[r0][k + 3];
      m1 += wv.x * dms[r1][k] + wv.y * dms[r1][k + 1] + wv.z * dms[r1][k + 2] + wv.w * dms[r1][k + 3];
    }
    ms[r0][h] = m0 * tau_s[r0];
    ms[r1][h] = m1 * tau_s[r1];
  }
  __syncthreads();

  // ---- Phase 4b: y = relu(Wa . m + ba) + Wr . x + br ----
  {
    float q0 = ba[h], q1 = q0, c0 = br[h], c1 = c0;
    const float4* wa = (const float4*)(Wa + (size_t)h * Dn);
    const float4* wr = (const float4*)(Wr + (size_t)h * Dn);
#pragma unroll 4
    for (int k4 = 0; k4 < Dn / 4; ++k4) {
      const float4 av = wa[k4];
      const float4 rv = wr[k4];
      const int k = k4 * 4;
      q0 += av.x * ms[r0][k] + av.y * ms[r0][k + 1] + av.z * ms[r0][k + 2] + av.w * ms[r0][k + 3];
      q1 += av.x * ms[r1][k] + av.y * ms[r1][k + 1] + av.z * ms[r1][k + 2] + av.w * ms[r1][k + 3];
      c0 += rv.x * xs[r0][k] + rv.y * xs[r0][k + 1] + rv.z * xs[r0][k + 2] + rv.w * xs[r0][k + 3];
      c1 += rv.x * xs[r1][k] + rv.y * xs[r1][k + 1] + rv.z * xs[r1][k + 2] + rv.w * xs[r1][k + 3];
    }
    ys[r0][h] = fmaxf(q0, 0.f) + c0;
    ys[r1][h] = fmaxf(q1, 0.f) + c1;
  }
  __syncthreads();

  // ---- Phase 5: LayerNorm (one wave per row) ----
  {
    const int r = t >> 6, p = t & 63;
    const float v0 = ys[r][p], v1 = ys[r][p + 64];
    float s = v0 + v1;
    float q = v0 * v0 + v1 * v1;
#pragma unroll
    for (int off = 32; off; off >>= 1) {
      s += __shfl_xor(s, off, 64);
      q += __shfl_xor(q, off, 64);
    }
    const float mu = s * (1.0f / 128.0f);
    const float var = q * (1.0f / 128.0f) - mu * mu;
    const float rs = rsqrtf(var + 1e-5f);
    float* o = out + (size_t)(i0 + r) * Hn;
    o[p]      = (v0 - mu) * rs * gamma[p]      + beta[p];
    o[p + 64] = (v1 - mu) * rs * gamma[p + 64] + beta[p + 64];
  }
}

extern "C" void kernel_launch(void* const* d_in, const int* in_sizes, int n_in,
                              void* d_out, int out_size, void* d_ws, size_t ws_size,
                              hipStream_t stream) {
  const float* x     = (const float*)d_in[0];
  const float* Wd    = (const float*)d_in[1];
  const float* bd    = (const float*)d_in[2];
  const float* Wt    = (const float*)d_in[3];
  const float* bt    = (const float*)d_in[4];
  const float* Wa    = (const float*)d_in[5];
  const float* ba    = (const float*)d_in[6];
  const float* Wr    = (const float*)d_in[7];
  const float* br    = (const float*)d_in[8];
  const float* gamma = (const float*)d_in[9];
  const float* beta  = (const float*)d_in[10];
  float* out = (float*)d_out;

  fused_resd1<<<Bn / 4, 256, 0, stream>>>(x, Wd, bd, Wt, bt, Wa, ba, Wr, br,
                                          gamma, beta, out);
  (void)in_sizes; (void)n_in; (void)out_size; (void)d_ws; (void)ws_size;
}

// Round 2
// 96.461 us; speedup vs baseline: 1.1387x; 1.1387x over previous
//
#include <hip/hip_runtime.h>
#include <math.h>

// B=1024, D=128, H=128
#define Bn 1024
#define Dn 128
#define Hn 128

// 256 blocks x 1024 threads. Block owns 4 i-rows.
// Phase 1: thread (g = t>>5 in [0,32), c = t&31 -> cols 4c..4c+3) accumulates
//   sum_j |x_i - x_j| over j in [32g, 32g+32) with float4 loads.
//   Per 16B load: 32 VALU instrs (4 rows x 4 cols x (sub + abs-add)).
//   16 waves/CU (4/SIMD) hide L2 latency; unroll-4 gives 4 loads in flight.
// Phase 2: LDS tree-reduce the 32 j-groups -> dms (diffs_mean rows).
// Phase 3: tau per row (wave shuffle reduce), t<256.
// Phase 4: matvecs m=(Wd.dm+bd)/tau ; y=relu(Wa.m+ba)+Wr.x+br, t<256.
// Phase 5: LayerNorm per row, t<256.
__global__ __launch_bounds__(1024) void fused_resd1(
    const float* __restrict__ x,
    const float* __restrict__ Wd, const float* __restrict__ bd,
    const float* __restrict__ Wt, const float* __restrict__ bt,
    const float* __restrict__ Wa, const float* __restrict__ ba,
    const float* __restrict__ Wr, const float* __restrict__ br,
    const float* __restrict__ gamma, const float* __restrict__ beta,
    float* __restrict__ out) {
  const int t = threadIdx.x;
  const int c = t & 31;   // column quad: cols 4c..4c+3
  const int g = t >> 5;   // j-group in [0,32)
  const int i0 = blockIdx.x << 2;

  __shared__ float red[32][4][Dn];  // 64 KB: per-group partial column sums
  __shared__ float xs[4][Dn];
  __shared__ float dms[4][Dn];
  __shared__ float ms[4][Hn];
  __shared__ float ys[4][Hn];
  __shared__ float wt_s[Dn];
  __shared__ float tau_s[4];        // 1/tau

  // ---- Phase 1: all-pairs partial sums ----
  float4 xi[4];
#pragma unroll
  for (int r = 0; r < 4; ++r)
    xi[r] = *(const float4*)(x + (size_t)(i0 + r) * Dn + c * 4);

  float4 acc[4];
#pragma unroll
  for (int r = 0; r < 4; ++r) acc[r] = make_float4(0.f, 0.f, 0.f, 0.f);

  const float4* xq = (const float4*)x + (size_t)g * 32 * (Dn / 4) + c;
#pragma unroll 1
  for (int jj = 0; jj < 32; jj += 4) {
    float4 xj[4];
#pragma unroll
    for (int u = 0; u < 4; ++u) xj[u] = xq[(size_t)(jj + u) * (Dn / 4)];
#pragma unroll
    for (int u = 0; u < 4; ++u) {
#pragma unroll
      for (int r = 0; r < 4; ++r) {
        acc[r].x += fabsf(xi[r].x - xj[u].x);
        acc[r].y += fabsf(xi[r].y - xj[u].y);
        acc[r].z += fabsf(xi[r].z - xj[u].z);
        acc[r].w += fabsf(xi[r].w - xj[u].w);
      }
    }
  }
#pragma unroll
  for (int r = 0; r < 4; ++r) *(float4*)&red[g][r][c * 4] = acc[r];
  __syncthreads();

  // ---- Phase 2: reduce 32 j-groups; stage xs, wt_s ----
  if (t < 512) {
    const int r = t >> 7, d = t & 127;
    float s = 0.f;
#pragma unroll
    for (int gg = 0; gg < 32; ++gg) s += red[gg][r][d];
    dms[r][d] = s * (1.0f / 1024.0f);
    xs[r][d] = x[(size_t)(i0 + r) * Dn + d];
  } else if (t < 640) {
    wt_s[t - 512] = Wt[t - 512];
  }
  __syncthreads();

  // ---- Phase 3: tau (one wave per row, t<256) ----
  if (t < 256) {
    const int r = t >> 6, p = t & 63;
    float partial = xs[r][p] * wt_s[p] + xs[r][p + 64] * wt_s[p + 64];
#pragma unroll
    for (int off = 32; off; off >>= 1) partial += __shfl_xor(partial, off, 64);
    if (p == 0) {
      const float z = partial + bt[0];
      const float sp = fmaxf(z, 0.f) + log1pf(expf(-fabsf(z)));  // softplus
      tau_s[r] = 1.0f / (fmaxf(sp, 0.01f) + 1.0f);
    }
  }
  __syncthreads();

  // ---- Phase 4a: m = (Wd . dm + bd) / tau (t<256) ----
  if (t < 256) {
    const int h = t & 127;
    const int g4 = t >> 7;
    const int r0 = 2 * g4, r1 = 2 * g4 + 1;
    float m0 = bd[h], m1 = m0;
    const float4* w = (const float4*)(Wd + (size_t)h * Dn);
#pragma unroll 4
    for (int k4 = 0; k4 < Dn / 4; ++k4) {
      const float4 wv = w[k4];
      const int k = k4 * 4;
      m0 += wv.x * dms[r0][k] + wv.y * dms[r0][k + 1] + wv.z * dms[r0][k + 2] + wv.w * dms[r0][k + 3];
      m1 += wv.x * dms[r1][k] + wv.y * dms[r1][k + 1] + wv.z * dms[r1][k + 2] + wv.w * dms[r1][k + 3];
    }
    ms[r0][h] = m0 * tau_s[r0];
    ms[r1][h] = m1 * tau_s[r1];
  }
  __syncthreads();

  // ---- Phase 4b: y = relu(Wa . m + ba) + Wr . x + br (t<256) ----
  if (t < 256) {
    const int h = t & 127;
    const int g4 = t >> 7;
    const int r0 = 2 * g4, r1 = 2 * g4 + 1;
    float q0 = ba[h], q1 = q0, c0 = br[h], c1 = c0;
    const float4* wa = (const float4*)(Wa + (size_t)h * Dn);
    const float4* wr = (const float4*)(Wr + (size_t)h * Dn);
#pragma unroll 4
    for (int k4 = 0; k4 < Dn / 4; ++k4) {
      const float4 av = wa[k4];
      const float4 rv = wr[k4];
      const int k = k4 * 4;
      q0 += av.x * ms[r0][k] + av.y * ms[r0][k + 1] + av.z * ms[r0][k + 2] + av.w * ms[r0][k + 3];
      q1 += av.x * ms[r1][k] + av.y * ms[r1][k + 1] + av.z * ms[r1][k + 2] + av.w * ms[r1][k + 3];
      c0 += rv.x * xs[r0][k] + rv.y * xs[r0][k + 1] + rv.z * xs[r0][k + 2] + rv.w * xs[r0][k + 3];
      c1 += rv.x * xs[r1][k] + rv.y * xs[r1][k + 1] + rv.z * xs[r1][k + 2] + rv.w * xs[r1][k + 3];
    }
    ys[r0][h] = fmaxf(q0, 0.f) + c0;
    ys[r1][h] = fmaxf(q1, 0.f) + c1;
  }
  __syncthreads();

  // ---- Phase 5: LayerNorm (one wave per row, t<256) ----
  if (t < 256) {
    const int r = t >> 6, p = t & 63;
    const float v0 = ys[r][p], v1 = ys[r][p + 64];
    float s = v0 + v1;
    float q = v0 * v0 + v1 * v1;
#pragma unroll
    for (int off = 32; off; off >>= 1) {
      s += __shfl_xor(s, off, 64);
      q += __shfl_xor(q, off, 64);
    }
    const float mu = s * (1.0f / 128.0f);
    const float var = q * (1.0f / 128.0f) - mu * mu;
    const float rs = rsqrtf(var + 1e-5f);
    float* o = out + (size_t)(i0 + r) * Hn;
    o[p]      = (v0 - mu) * rs * gamma[p]      + beta[p];
    o[p + 64] = (v1 - mu) * rs * gamma[p + 64] + beta[p + 64];
  }
}

extern "C" void kernel_launch(void* const* d_in, const int* in_sizes, int n_in,
                              void* d_out, int out_size, void* d_ws, size_t ws_size,
                              hipStream_t stream) {
  const float* x     = (const float*)d_in[0];
  const float* Wd    = (const float*)d_in[1];
  const float* bd    = (const float*)d_in[2];
  const float* Wt    = (const float*)d_in[3];
  const float* bt    = (const float*)d_in[4];
  const float* Wa    = (const float*)d_in[5];
  const float* ba    = (const float*)d_in[6];
  const float* Wr    = (const float*)d_in[7];
  const float* br    = (const float*)d_in[8];
  const float* gamma = (const float*)d_in[9];
  const float* beta  = (const float*)d_in[10];
  float* out = (float*)d_out;

  fused_resd1<<<Bn / 4, 1024, 0, stream>>>(x, Wd, bd, Wt, bt, Wa, ba, Wr, br,
                                           gamma, beta, out);
  (void)in_sizes; (void)n_in; (void)out_size; (void)d_ws; (void)ws_size;
}